// Round 5
// baseline (13.899 us; speedup 1.0000x reference)
//
#include <hip/hip_runtime.h>

#define MARGIN 0.5f
#define NROWS 4096
#define D 128
#define BLK_WAVES 16                       // 1024 threads, 1 wave per row
#define NBLK (NROWS / BLK_WAVES)           // 256 blocks (power of 2: ticket mod trick)

// Single fused kernel, fence-free last-block reduction:
//  - per wave: ballot-compact negs / pos constants into wave-private LDS,
//    float4 broadcast inner loop, wave reduce -> row mean
//  - block reduce -> (sum, valid) packed into one u64
//  - relaxed agent-scope atomic_exchange into slot[blockIdx]  (performed at LLC)
//  - s_waitcnt vmcnt(0)  -> xchg performed BEFORE ticket RMW issues
//  - relaxed ticket fetch_add; last block re-reads all slots via relaxed
//    agent atomic loads (LLC-direct, no stale L2) and writes the scalar.
//  No release/acquire fences -> no per-block L2 writeback/invalidate storms.
__global__ __launch_bounds__(1024) void mrl_fused_kernel(
    const float* __restrict__ logits,
    const int*   __restrict__ labels,
    unsigned long long* __restrict__ slots,   // [NBLK] packed (S,V)
    unsigned int*       __restrict__ ticket,  // [1] never reset; modulo trick
    float*              __restrict__ out)
{
    const int wave = threadIdx.x >> 6;     // 0..15
    const int lane = threadIdx.x & 63;
    const int row  = blockIdx.x * BLK_WAVES + wave;

    __shared__ float  s_neg[BLK_WAVES][132];
    __shared__ float  s_pos[BLK_WAVES][132];
    __shared__ float2 sw[BLK_WAVES];
    __shared__ int    s_last;

    const float* lrow   = logits + (size_t)row * D;
    const int*   labrow = labels + (size_t)row * D;

    const int i0 = lane * 2;
    float2 lv = *reinterpret_cast<const float2*>(lrow + i0);
    int2   bv = *reinterpret_cast<const int2*>(labrow + i0);

    const bool n0 = (bv.x == 0), n1 = (bv.y == 0);
    const bool p0 = (bv.x > 0),  p1 = (bv.y > 0);

    const unsigned long long mn0 = __ballot(n0);
    const unsigned long long mn1 = __ballot(n1);
    const unsigned long long mp0 = __ballot(p0);
    const unsigned long long mp1 = __ballot(p1);
    const unsigned long long below = (1ull << lane) - 1ull;

    const int nneg = __popcll(mn0) + __popcll(mn1);
    const int npos = __popcll(mp0) + __popcll(mp1);

    if (n0) s_neg[wave][__popcll(mn0 & below)]                 = lv.x;
    if (n1) s_neg[wave][__popcll(mn0) + __popcll(mn1 & below)] = lv.y;
    if (p0) s_pos[wave][__popcll(mp0 & below)]                 = MARGIN - lv.x;
    if (p1) s_pos[wave][__popcll(mp0) + __popcll(mp1 & below)] = MARGIN - lv.y;

    // pad negs to x4 with -BIG so fmax(neg + c, 0) == 0
    if (lane < 4) s_neg[wave][nneg + lane] = -3.0e38f;

    // wave-private LDS region: wave64 lockstep + in-order LDS pipe
    __builtin_amdgcn_wave_barrier();

    const int nneg4 = (nneg + 3) >> 2;
    const float4* vp = reinterpret_cast<const float4*>(s_neg[wave]);

    float acc = 0.f;
    for (int p = lane; p < npos; p += 64) {
        const float c = s_pos[wave][p];
        float a = 0.f;
#pragma unroll 2
        for (int q = 0; q < nneg4; ++q) {
            float4 v = vp[q];              // broadcast read, conflict-free
            a += fmaxf(v.x + c, 0.f);
            a += fmaxf(v.y + c, 0.f);
            a += fmaxf(v.z + c, 0.f);
            a += fmaxf(v.w + c, 0.f);
        }
        acc += a;
    }

    for (int off = 32; off > 0; off >>= 1)
        acc += __shfl_xor(acc, off);

    if (lane == 0) {
        const int cnt = npos * nneg;
        sw[wave] = (cnt > 0) ? make_float2(acc / (float)cnt, 1.f)
                             : make_float2(0.f, 0.f);
    }
    __syncthreads();

    if (threadIdx.x == 0) {
        float S = 0.f, V = 0.f;
#pragma unroll
        for (int w = 0; w < BLK_WAVES; ++w) { S += sw[w].x; V += sw[w].y; }

        const unsigned long long packed =
            ((unsigned long long)__float_as_uint(V) << 32) | __float_as_uint(S);

        unsigned long long old = __hip_atomic_exchange(
            &slots[blockIdx.x], packed, __ATOMIC_RELAXED, __HIP_MEMORY_SCOPE_AGENT);
        // ensure the xchg has PERFORMED at the LLC before the ticket RMW
        // issues; consume `old` + memory clobber pins ordering.
        asm volatile("s_waitcnt vmcnt(0)" :: "v"(old) : "memory");

        const unsigned int t = __hip_atomic_fetch_add(
            ticket, 1u, __ATOMIC_RELAXED, __HIP_MEMORY_SCOPE_AGENT);
        // exactly one block per launch, for any (poisoned) starting value
        s_last = (((t + 1u) & (NBLK - 1u)) == 0u) ? 1 : 0;
    }
    __syncthreads();
    if (!s_last) return;

    // ---- last block: fixed-order reduce of 256 slots (deterministic) ----
    float2 t = make_float2(0.f, 0.f);
    if (threadIdx.x < NBLK) {
        const unsigned long long v = __hip_atomic_load(
            &slots[threadIdx.x], __ATOMIC_RELAXED, __HIP_MEMORY_SCOPE_AGENT);
        t.x = __uint_as_float((unsigned int)(v & 0xffffffffull));
        t.y = __uint_as_float((unsigned int)(v >> 32));
    }
    for (int off = 32; off > 0; off >>= 1) {
        t.x += __shfl_xor(t.x, off);
        t.y += __shfl_xor(t.y, off);
    }
    __syncthreads();                       // sw reuse is safe after this
    if (lane == 0) sw[wave] = t;           // waves >= 4 contribute zeros
    __syncthreads();
    if (threadIdx.x == 0) {
        float S = 0.f, V = 0.f;
#pragma unroll
        for (int w = 0; w < BLK_WAVES; ++w) { S += sw[w].x; V += sw[w].y; }
        out[0] = (V > 0.f) ? S / V : 0.f;
    }
}

extern "C" void kernel_launch(void* const* d_in, const int* in_sizes, int n_in,
                              void* d_out, int out_size, void* d_ws, size_t ws_size,
                              hipStream_t stream) {
    const float* logits = (const float*)d_in[0];
    const int*   labels = (const int*)d_in[1];
    float* out = (float*)d_out;
    // ws layout: [0 .. NBLK) u64 slots | ticket (uint) right after
    unsigned long long* slots  = (unsigned long long*)d_ws;
    unsigned int*       ticket = (unsigned int*)(slots + NBLK);

    mrl_fused_kernel<<<NBLK, 1024, 0, stream>>>(logits, labels, slots, ticket, out);
}

// Round 6
// 11.893 us; speedup vs baseline: 1.1687x; 1.1687x over previous
//
#include <hip/hip_runtime.h>

#define MARGIN 0.5f
#define NROWS 4096
#define D 128
#define ROWS_PER_BLOCK 4                   // 4 waves/block, 1 wave per row
#define NBLK (NROWS / ROWS_PER_BLOCK)      // 1024 blocks

// Kernel 1: one wave per row, 4 waves/block (R2's best-measured shape).
//  - ballot-compact negative logits / positive constants into wave-private LDS
//  - float4 broadcast reads over compacted negatives
//  - wave reduce -> row mean; tiny LDS reduce -> ONE packed float2 store/block
__global__ __launch_bounds__(256) void mrl_row_kernel(
    const float* __restrict__ logits,
    const int*   __restrict__ labels,
    float2* __restrict__ partial)          // [NBLK] = (sum row means, valid cnt)
{
    const int wave = threadIdx.x >> 6;
    const int lane = threadIdx.x & 63;
    const int row  = blockIdx.x * ROWS_PER_BLOCK + wave;

    __shared__ float  s_neg[ROWS_PER_BLOCK][132];
    __shared__ float  s_pos[ROWS_PER_BLOCK][132];
    __shared__ float2 sw[ROWS_PER_BLOCK];

    const float* lrow   = logits + (size_t)row * D;
    const int*   labrow = labels + (size_t)row * D;

    const int i0 = lane * 2;
    float2 lv = *reinterpret_cast<const float2*>(lrow + i0);
    int2   bv = *reinterpret_cast<const int2*>(labrow + i0);

    const bool n0 = (bv.x == 0), n1 = (bv.y == 0);
    const bool p0 = (bv.x > 0),  p1 = (bv.y > 0);

    const unsigned long long mn0 = __ballot(n0);
    const unsigned long long mn1 = __ballot(n1);
    const unsigned long long mp0 = __ballot(p0);
    const unsigned long long mp1 = __ballot(p1);
    const unsigned long long below = (1ull << lane) - 1ull;

    const int nneg = __popcll(mn0) + __popcll(mn1);
    const int npos = __popcll(mp0) + __popcll(mp1);

    if (n0) s_neg[wave][__popcll(mn0 & below)]                 = lv.x;
    if (n1) s_neg[wave][__popcll(mn0) + __popcll(mn1 & below)] = lv.y;
    if (p0) s_pos[wave][__popcll(mp0 & below)]                 = MARGIN - lv.x;
    if (p1) s_pos[wave][__popcll(mp0) + __popcll(mp1 & below)] = MARGIN - lv.y;

    // pad negs to x4 with -BIG so fmax(neg + c, 0) == 0
    if (lane < 4) s_neg[wave][nneg + lane] = -3.0e38f;

    // wave-private LDS region: wave64 lockstep + in-order LDS pipe; only
    // prevent compiler reordering of the reads above the writes.
    __builtin_amdgcn_wave_barrier();

    const int nneg4 = (nneg + 3) >> 2;
    const float4* vp = reinterpret_cast<const float4*>(s_neg[wave]);

    float acc = 0.f;
    for (int p = lane; p < npos; p += 64) {
        const float c = s_pos[wave][p];
        float a = 0.f;
#pragma unroll 2
        for (int q = 0; q < nneg4; ++q) {
            float4 v = vp[q];              // broadcast read, conflict-free
            a += fmaxf(v.x + c, 0.f);
            a += fmaxf(v.y + c, 0.f);
            a += fmaxf(v.z + c, 0.f);
            a += fmaxf(v.w + c, 0.f);
        }
        acc += a;
    }

    for (int off = 32; off > 0; off >>= 1)
        acc += __shfl_xor(acc, off);

    if (lane == 0) {
        const int cnt = npos * nneg;
        sw[wave] = (cnt > 0) ? make_float2(acc / (float)cnt, 1.f)
                             : make_float2(0.f, 0.f);
    }
    __syncthreads();

    if (threadIdx.x == 0) {
        float2 t0 = sw[0], t1 = sw[1], t2 = sw[2], t3 = sw[3];
        partial[blockIdx.x] = make_float2(t0.x + t1.x + t2.x + t3.x,
                                          t0.y + t1.y + t2.y + t3.y);
    }
}

// Kernel 2: one 1024-thread block, ONE coalesced float2 round over 1024 partials.
__global__ __launch_bounds__(1024) void mrl_reduce_kernel(
    const float2* __restrict__ partial,
    float* __restrict__ out)
{
    float2 t = partial[threadIdx.x];
    for (int off = 32; off > 0; off >>= 1) {
        t.x += __shfl_xor(t.x, off);
        t.y += __shfl_xor(t.y, off);
    }
    __shared__ float2 sw[16];
    const int wave = threadIdx.x >> 6;
    const int lane = threadIdx.x & 63;
    if (lane == 0) sw[wave] = t;
    __syncthreads();
    if (threadIdx.x == 0) {
        float S = 0.f, V = 0.f;
#pragma unroll
        for (int w = 0; w < 16; ++w) { S += sw[w].x; V += sw[w].y; }
        out[0] = (V > 0.f) ? S / V : 0.f;
    }
}

extern "C" void kernel_launch(void* const* d_in, const int* in_sizes, int n_in,
                              void* d_out, int out_size, void* d_ws, size_t ws_size,
                              hipStream_t stream) {
    const float* logits = (const float*)d_in[0];
    const int*   labels = (const int*)d_in[1];
    float* out = (float*)d_out;
    float2* partial = (float2*)d_ws;       // 1024 * 8 B

    mrl_row_kernel<<<NBLK, 256, 0, stream>>>(logits, labels, partial);
    mrl_reduce_kernel<<<1, 1024, 0, stream>>>(partial, out);
}